// Round 6
// baseline (3878.720 us; speedup 1.0000x reference)
//
#include <hip/hip_runtime.h>
#include <math.h>

#define T_   32
#define N_   64
#define NL   64
#define E_   128
#define G3   384   // 3*E
#define NE   4
#define CH   64
#define D_   16
#define HW   16
#define RH   64
#define LE   64
#define HD   512
#define A_   16
#define INVN 32
#define KCOLS 9216 // CH*D_*3*3
#define OUTW 663

typedef _Float16 half8 __attribute__((ext_vector_type(8)));
typedef float floatx4 __attribute__((ext_vector_type(4)));

__device__ __forceinline__ float sigf(float x) { return 1.f/(1.f+expf(-x)); }
// fast versions (v_exp_f32 + v_rcp_f32, ~1e-6 rel err)
__device__ __forceinline__ float fsig(float x)  { return __builtin_amdgcn_rcpf(1.f + __expf(-x)); }
__device__ __forceinline__ float ftanh(float x) { return 1.f - 2.f*__builtin_amdgcn_rcpf(1.f + __expf(2.f*x)); }

// ---------------- prep kernels ----------------

__global__ __launch_bounds__(128) void k_prep_M(const int* lines, const float* emb_task, float* M) {
    int nl = blockIdx.x;
    int i  = threadIdx.x;
    const int* ln = lines + nl*4;
    float s = 0.f;
    #pragma unroll
    for (int t = 0; t < 4; ++t) s += emb_task[ln[t]*E_ + i];
    M[nl*E_ + i] = s;
}

__global__ __launch_bounds__(256) void k_zero(int* cnt) {
    int i = blockIdx.x*256 + threadIdx.x;
    if (i < 32 + 32*64) cnt[i] = 0;
}

// wiT4[((dir*32 + k/4)*384 + g)*4 + (k%4)] = wi[dir][g*128+k]
__global__ __launch_bounds__(128) void k_prep_T4(const float* wif, const float* wib, float* wiT4) {
    int g = blockIdx.x % 384, dir = blockIdx.x / 384;
    int k = threadIdx.x;
    const float* wi = dir ? wib : wif;
    int dst = ((dir*32 + (k>>2))*384 + g)*4 + (k&3);
    wiT4[dst] = wi[g*128 + k];
}

// pack Wh into per-wave fp16 hi/lo B-fragments.
__global__ __launch_bounds__(64) void k_packW(const float* whf, const float* whb, _Float16* WBpack) {
    int f = blockIdx.x;        // 0..383
    int lane = threadIdx.x;
    int nt = f % 6; int rest = f / 6;
    int term = rest % 2; rest /= 2;
    int kt = rest % 4; rest /= 4;
    int w = rest % 4; int dir = rest / 4;
    const float* wh = dir ? whb : whf;
    int gt = nt >> 1, isub = nt & 1;
    int g  = gt*128 + w*32 + isub*16 + (lane & 15);
    int k0 = kt*32 + (lane >> 4)*8;
    _Float16* dst = WBpack + (size_t)f*512 + lane*8;
    #pragma unroll
    for (int e = 0; e < 8; ++e) {
        float v = wh[g*128 + k0 + e];
        _Float16 hi = (_Float16)v;
        dst[e] = (term == 0) ? hi : (_Float16)(v - (float)hi);
    }
}

__global__ __launch_bounds__(128) void k_prep_misc(const int* p0, const float* M, int* p_cur, float* mp) {
    int n = blockIdx.x, i = threadIdx.x;
    int p = p0[n];
    if (i == 0) p_cur[n] = p;
    mp[n*E_ + i] = M[(n*NL + p)*E_ + i];
}

__global__ __launch_bounds__(64) void k_prep_invpa(const float* inv, const float* inv_w, const float* inv_b,
                                                   const int* pa, const float* emb_lower,
                                                   float* inv_all, float* pa_all) {
    int tn = blockIdx.x, r = threadIdx.x;
    const float* iv = inv + tn*INVN;
    float acc = inv_b[r];
    #pragma unroll
    for (int i = 0; i < INVN; ++i) acc += iv[i]*inv_w[i*RH + r];
    inv_all[tn*RH + r] = fmaxf(acc, 0.f);
    const int* pp = pa + tn*4;
    float s = 0.f;
    #pragma unroll
    for (int j = 0; j < 4; ++j) s += emb_lower[pp[j]*LE + r];
    pa_all[tn*LE + r] = s;
}

// giM[dir][n][l][g] = M[n][l] . wi[g] + bi[g]
__global__ __launch_bounds__(384) void k_giM(const float* M, const float* wiT4,
                                             const float* bif, const float* bib, float* giM) {
    int lblk = blockIdx.x, n = blockIdx.y, dir = blockIdx.z;
    int g = threadIdx.x;
    __shared__ float Ml[8][E_];
    for (int idx = g; idx < 8*E_; idx += 384) {
        int r = idx >> 7, k = idx & 127;
        Ml[r][k] = M[(n*NL + lblk*8 + r)*E_ + k];
    }
    __syncthreads();
    float acc[8];
    #pragma unroll
    for (int r = 0; r < 8; ++r) acc[r] = 0.f;
    const float4* W = (const float4*)(wiT4) + dir*32*384;
    for (int kq = 0; kq < 32; ++kq) {
        float4 w = W[kq*384 + g];
        #pragma unroll
        for (int r = 0; r < 8; ++r) {
            float4 h = *(const float4*)&Ml[r][kq*4];
            acc[r] += w.x*h.x + w.y*h.y + w.z*h.z + w.w*h.w;
        }
    }
    float bi = dir ? bib[g] : bif[g];
    #pragma unroll
    for (int r = 0; r < 8; ++r)
        giM[((dir*N_ + n)*NL + lblk*8 + r)*G3 + g] = acc[r] + bi;
}

// ---------------- MFMA GRU ----------------
__global__ __launch_bounds__(256, 1) void k_gru(const float* giM, const _Float16* WBpack,
                                                const float* bhf, const float* bhb,
                                                const float* beta_w, const float* beta_b,
                                                float* Ball) {
    int half = blockIdx.x, n = blockIdx.y, dir = blockIdx.z;
    int tid = threadIdx.x;
    int w = tid >> 6;
    int lane = tid & 63;
    int quad = lane >> 4;
    int col  = lane & 15;

    __shared__ _Float16 Hhi[32*136];
    __shared__ _Float16 Hlo[32*136];
    __shared__ float    Hf[32*132];
    __shared__ float    bwT[4*132];
    for (int idx = tid; idx < 32*136; idx += 256) { Hhi[idx] = (_Float16)0.f; Hlo[idx] = (_Float16)0.f; }
    for (int idx = tid; idx < 32*132; idx += 256) Hf[idx] = 0.f;
    for (int idx = tid; idx < 512; idx += 256) { int k = idx >> 2, e = idx & 3; bwT[e*132 + k] = beta_w[k*NE + e]; }

    half8 WB[48];
    const half8* wsrc = (const half8*)(WBpack) + ((size_t)(dir*4 + w)*4)*12*64;
    #pragma unroll
    for (int f = 0; f < 48; ++f) WB[f] = wsrc[(size_t)f*64 + lane];

    const float* bh = dir ? bhb : bhf;
    float bhv[6];
    #pragma unroll
    for (int gt2 = 0; gt2 < 3; ++gt2) {
        bhv[gt2*2+0] = bh[gt2*128 + w*32 + col];
        bhv[gt2*2+1] = bh[gt2*128 + w*32 + col + 16];
    }
    const float* giBase = giM + (size_t)(dir*N_ + n)*NL*G3;

    int bseq = tid >> 3, bsub = tid & 7, bee = bsub & 3, bpart = bsub >> 2;
    float bbias = beta_b[bee];
    __syncthreads();

    for (int j = 0; j < NL; ++j) {
        floatx4 C[12];
        #pragma unroll
        for (int Mt = 0; Mt < 2; ++Mt) {
            #pragma unroll
            for (int reg = 0; reg < 4; ++reg) {
                int seq = Mt*16 + quad*4 + reg;
                int p = half*32 + seq;
                int l = dir ? ((p + 63 - j) & 63) : ((p + j) & 63);
                const float* gl = giBase + l*G3 + w*32 + col;
                #pragma unroll
                for (int gt2 = 0; gt2 < 2; ++gt2)
                    #pragma unroll
                    for (int isub = 0; isub < 2; ++isub)
                        C[Mt*6 + gt2*2 + isub][reg] = gl[gt2*128 + isub*16] + bhv[gt2*2+isub];
                #pragma unroll
                for (int isub = 0; isub < 2; ++isub)
                    C[Mt*6 + 4 + isub][reg] = bhv[4+isub];
            }
        }
        #pragma unroll
        for (int kt = 0; kt < 4; ++kt) {
            half8 ahi[2], alo[2];
            #pragma unroll
            for (int Mt = 0; Mt < 2; ++Mt) {
                int off = (Mt*16 + col)*136 + kt*32 + quad*8;
                ahi[Mt] = *(const half8*)&Hhi[off];
                alo[Mt] = *(const half8*)&Hlo[off];
            }
            #pragma unroll
            for (int nt = 0; nt < 6; ++nt) {
                half8 bhi2 = WB[kt*12 + nt];
                half8 blo2 = WB[kt*12 + 6 + nt];
                #pragma unroll
                for (int Mt = 0; Mt < 2; ++Mt) {
                    C[Mt*6+nt] = __builtin_amdgcn_mfma_f32_16x16x32_f16(ahi[Mt], bhi2, C[Mt*6+nt], 0,0,0);
                    C[Mt*6+nt] = __builtin_amdgcn_mfma_f32_16x16x32_f16(alo[Mt], bhi2, C[Mt*6+nt], 0,0,0);
                    C[Mt*6+nt] = __builtin_amdgcn_mfma_f32_16x16x32_f16(ahi[Mt], blo2, C[Mt*6+nt], 0,0,0);
                }
            }
        }
        __syncthreads();

        #pragma unroll
        for (int Mt = 0; Mt < 2; ++Mt) {
            #pragma unroll
            for (int reg = 0; reg < 4; ++reg) {
                int seq = Mt*16 + quad*4 + reg;
                int p = half*32 + seq;
                int l = dir ? ((p + 63 - j) & 63) : ((p + j) & 63);
                const float* gl = giBase + l*G3 + 256 + w*32 + col;
                #pragma unroll
                for (int isub = 0; isub < 2; ++isub) {
                    int i = w*32 + isub*16 + col;
                    float r  = fsig(C[Mt*6 + isub][reg]);
                    float z  = fsig(C[Mt*6 + 2 + isub][reg]);
                    float nn = ftanh(gl[isub*16] + r*C[Mt*6 + 4 + isub][reg]);
                    float hold = Hf[seq*132 + i];
                    float hnew = (1.f - z)*nn + z*hold;
                    _Float16 hi = (_Float16)hnew;
                    _Float16 lo = (_Float16)(hnew - (float)hi);
                    Hf[seq*132 + i] = hnew;
                    Hhi[seq*136 + i] = hi;
                    Hlo[seq*136 + i] = lo;
                }
            }
        }
        __syncthreads();

        {
            float acc = 0.f;
            const float* hrow = &Hf[bseq*132];
            const float* brow = &bwT[bee*132];
            #pragma unroll 8
            for (int kk = 0; kk < 64; ++kk) {
                int k2 = bpart + 2*kk;
                acc += hrow[k2]*brow[k2];
            }
            acc += __shfl_xor(acc, 4);
            if (bpart == 0) {
                float bval = fsig(acc + bbias);
                int p = half*32 + bseq;
                Ball[((n*NL + p)*128 + 2*j + dir)*NE + bee] = bval;
            }
        }
    }
}

// stick-breaking -> reordered P_final[n][p][j][e]
__global__ __launch_bounds__(64) void k_P(const float* Ball, float* Pall) {
    int np = blockIdx.x;
    int tid = threadIdx.x;
    __shared__ float B[128][NE];
    __shared__ float Pf[128][NE];
    const float* src = Ball + np*128*NE;
    for (int idx = tid; idx < 128*NE; idx += 64) ((float*)B)[idx] = src[idx];
    __syncthreads();
    if (tid < NE) {
        int e = tid;
        float c = 1.f;
        for (int j2 = 0; j2 < 128; ++j2) {
            float bz = (j2 == 0 || j2 == 127) ? 0.f : B[j2][e];
            float bf = (j2 == 127) ? 1.f : bz;
            Pf[j2][e] = bf * c;
            c *= (1.f - bz);
        }
    }
    __syncthreads();
    float* dst = Pall + np*128*NE;
    for (int idx = tid; idx < 128*NE; idx += 64) {
        int j = idx >> 2, e = idx & 3;
        int jf = (j < 64) ? (2*(63 - j) + 1) : (2*(j - 64));
        dst[idx] = Pf[jf][e];
    }
}

// ---------------- head-GEMM precomputes ----------------
__global__ __launch_bounds__(256) void k_zmp(const float* M, const float* zw, float* zmp) {
    int cb = blockIdx.x, rb = blockIdx.y;
    int tid = threadIdx.x;
    __shared__ float At[32][E_];
    for (int idx = tid; idx < 32*E_; idx += 256) {
        int r = idx >> 7, k = idx & 127;
        At[r][k] = M[(rb*32 + r)*E_ + k];
    }
    __syncthreads();
    float acc[32];
    #pragma unroll
    for (int r = 0; r < 32; ++r) acc[r] = 0.f;
    int col = cb*256 + tid;
    #pragma unroll 4
    for (int k = 0; k < E_; ++k) {
        float w = zw[k*HD + col];
        #pragma unroll
        for (int r = 0; r < 32; ++r) acc[r] += At[r][k]*w;
    }
    #pragma unroll
    for (int r = 0; r < 32; ++r)
        zmp[(size_t)(rb*32 + r)*HD + col] = acc[r];
}

__global__ __launch_bounds__(256) void k_ip(const float* inv_all, const float* pa_all,
                                            const float* zw, const float* zb, float* zip) {
    int cb = blockIdx.x, rb = blockIdx.y;
    int tid = threadIdx.x;
    __shared__ float At[32][E_];
    for (int idx = tid; idx < 32*E_; idx += 256) {
        int r = idx >> 7, k = idx & 127;
        int row = rb*32 + r;
        At[r][k] = (k < 64) ? inv_all[row*RH + k] : pa_all[row*LE + (k - 64)];
    }
    __syncthreads();
    float acc[32];
    #pragma unroll
    for (int r = 0; r < 32; ++r) acc[r] = 0.f;
    int col = cb*256 + tid;
    #pragma unroll 4
    for (int k = 0; k < E_; ++k) {
        float w = zw[(192 + k)*HD + col];
        #pragma unroll
        for (int r = 0; r < 32; ++r) acc[r] += At[r][k]*w;
    }
    float b = zb[col];
    #pragma unroll
    for (int r = 0; r < 32; ++r)
        zip[(size_t)(rb*32 + r)*HD + col] = acc[r] + b;
}

__global__ __launch_bounds__(256) void k_mpsmall(const float* M, const float* uw, const float* dw,
                                                 float* ump, float* dmp) {
    int wg = blockIdx.x;
    int tid = threadIdx.x;
    __shared__ float Mt[64][E_];
    for (int idx = tid; idx < 64*E_; idx += 256)
        ((float*)Mt)[idx] = M[(size_t)wg*64*E_ + idx];
    __syncthreads();
    int r = tid >> 2, q = tid & 3;
    float au = 0.f, ad = 0.f;
    #pragma unroll 4
    for (int k = 0; k < E_; ++k) {
        float m = Mt[r][k];
        au += m*uw[k*NE + q];
        if (q < 2) ad += m*dw[k*2 + q];
    }
    int row = wg*64 + r;
    ump[row*NE + q] = au;
    if (q < 2) dmp[row*2 + q] = ad;
}

__global__ __launch_bounds__(256) void k_ipsmall(const float* inv_all, const float* pa_all,
                                                 const float* uw, const float* ub,
                                                 const float* dw, const float* db,
                                                 float* uip, float* dip) {
    int wg = blockIdx.x;
    int tid = threadIdx.x;
    __shared__ float At[64][E_];
    for (int idx = tid; idx < 64*E_; idx += 256) {
        int r = idx >> 7, k = idx & 127;
        int row = wg*64 + r;
        At[r][k] = (k < 64) ? inv_all[row*RH + k] : pa_all[row*LE + (k - 64)];
    }
    __syncthreads();
    int r = tid >> 2, q = tid & 3;
    float au = ub[q], ad = (q < 2) ? db[q] : 0.f;
    #pragma unroll 4
    for (int k = 0; k < E_; ++k) {
        float v = At[r][k];
        au += v*uw[(192 + k)*NE + q];
        if (q < 2) ad += v*dw[(192 + k)*2 + q];
    }
    int row = wg*64 + r;
    uip[row*NE + q] = au;
    if (q < 2) dip[row*2 + q] = ad;
}

// ---------------- fused per-step kernel ----------------
// grid 256 wgs (q = wg&3, n = wg>>2), 256 thr. Phases inside one dispatch:
//  1) kern GEMM: wg computes cols [wg*36, wg*36+36) for all n -> kern_bufT[col][n]
//     (kernel_w read exactly once per step), release-count cnt_kern[t].
//  2) conv: acquire-spin cnt_kern[t]==256; quarter q, sample n -> h1_buf,
//     release-count cnt_conv[t*64+n].
//  3) heads (q==0 only): acquire-spin cnt_conv==4; heads + pointer update.
__global__ __launch_bounds__(256) void k_step(
    const float* obs, const float* kernel_w, const float* kernel_b, const float* conv_bias,
    float* kern_bufT, float* h1_buf,
    const float* zmp, const float* zip,
    const float* ump, const float* uip, const float* dmp, const float* dip,
    const float* zw, const float* aw, const float* ab,
    const float* uw, const float* dw, const float* cw, const float* cb,
    const float* amask, const float* Pall, const float* M,
    float* mp_buf, int* p_cur, float* out,
    int* cnt_kern, int* cnt_conv, int t) {

    int wg = blockIdx.x, tid = threadIdx.x;
    int q = wg & 3, n = wg >> 2;
    __shared__ __align__(16) char smem[58368];

    // ---- phase 1: kern GEMM ----
    {
        float* mpT = (float*)smem;                    // [k][66-pad]
        float* kw  = (float*)(smem + 33792);          // [(k*4+cq)*12 + j]
        for (int idx = tid; idx < N_*E_; idx += 256) {
            int nn = idx >> 7, k = idx & 127;
            mpT[k*66 + nn] = mp_buf[idx];
        }
        const float* kwsrc = kernel_w + wg*36;
        for (int idx = tid; idx < 128*36; idx += 256) {
            int k = idx / 36, r = idx - k*36;
            int cq2 = r / 9, j2 = r - cq2*9;
            kw[(k*4 + cq2)*12 + j2] = kwsrc[k*KCOLS + r];
        }
        __syncthreads();
        int cq = tid >> 6, n2 = tid & 63;
        float acc[9];
        #pragma unroll
        for (int j2 = 0; j2 < 9; ++j2) acc[j2] = kernel_b[wg*36 + cq*9 + j2];
        #pragma unroll 4
        for (int k = 0; k < 128; ++k) {
            float m = mpT[k*66 + n2];
            const float* kwr = &kw[(k*4 + cq)*12];
            #pragma unroll
            for (int j2 = 0; j2 < 9; ++j2) acc[j2] += m * kwr[j2];
        }
        #pragma unroll
        for (int j2 = 0; j2 < 9; ++j2)
            kern_bufT[(size_t)(wg*36 + cq*9 + j2)*64 + n2] = acc[j2];
    }
    __threadfence();
    __syncthreads();
    if (tid == 0) __hip_atomic_fetch_add(&cnt_kern[t], 1, __ATOMIC_RELEASE, __HIP_MEMORY_SCOPE_AGENT);

    // ---- phase 2: conv ----
    if (tid == 0) {
        while (__hip_atomic_load(&cnt_kern[t], __ATOMIC_ACQUIRE, __HIP_MEMORY_SCOPE_AGENT) < 256) {}
    }
    __syncthreads();
    {
        float* obs_l = (float*)smem;                  // [d][y][20-pad], 20480 B
        float* kl    = (float*)(smem + 20480);        // 2304 floats
        const float4* op4 = (const float4*)(obs + (size_t)(t*N_ + n)*D_*HW*HW);
        #pragma unroll
        for (int k = 0; k < 4; ++k) {
            int idx = tid + k*256;
            int d = idx >> 6, rem = idx & 63;
            int y = rem >> 2, xq = rem & 3;
            *(float4*)&obs_l[d*320 + y*20 + xq*4] = op4[idx];
        }
        for (int c = tid; c < 2304; c += 256)
            kl[c] = kern_bufT[(size_t)(q*2304 + c)*64 + n];
        __syncthreads();

        int c = tid >> 4, y = tid & 15;
        float acc[16];
        #pragma unroll
        for (int x = 0; x < 16; ++x) acc[x] = 0.f;
        for (int d = 0; d < D_; ++d) {
            const float* kd = &kl[c*144 + d*9];
            #pragma unroll
            for (int ky = 0; ky < 3; ++ky) {
                int yy = y + ky - 1;
                if (yy < 0 || yy >= HW) continue;
                const float4* rs = (const float4*)&obs_l[(d*16 + yy)*20];
                float4 r0 = rs[0], r1 = rs[1], r2 = rs[2], r3 = rs[3];
                float row[18];
                row[0] = 0.f; row[17] = 0.f;
                row[1]=r0.x; row[2]=r0.y; row[3]=r0.z; row[4]=r0.w;
                row[5]=r1.x; row[6]=r1.y; row[7]=r1.z; row[8]=r1.w;
                row[9]=r2.x; row[10]=r2.y; row[11]=r2.z; row[12]=r2.w;
                row[13]=r3.x; row[14]=r3.y; row[15]=r3.z; row[16]=r3.w;
                float k0 = kd[ky*3], k1 = kd[ky*3+1], k2 = kd[ky*3+2];
                #pragma unroll
                for (int x = 0; x < 16; ++x)
                    acc[x] += row[x]*k0 + row[x+1]*k1 + row[x+2]*k2;
            }
        }
        float bc = conv_bias[q*16 + c];
        float psum = 0.f;
        #pragma unroll
        for (int x = 0; x < 16; ++x) psum += fmaxf(acc[x] + bc, 0.f);
        psum += __shfl_xor(psum, 1);
        psum += __shfl_xor(psum, 2);
        psum += __shfl_xor(psum, 4);
        psum += __shfl_xor(psum, 8);
        if (y == 0) h1_buf[n*CH + q*16 + c] = psum;
    }
    __threadfence();
    __syncthreads();
    if (tid == 0) __hip_atomic_fetch_add(&cnt_conv[t*64 + n], 1, __ATOMIC_RELEASE, __HIP_MEMORY_SCOPE_AGENT);

    // ---- phase 3: heads (q==0 wgs only) ----
    if (q != 0) return;
    if (tid == 0) {
        while (__hip_atomic_load(&cnt_conv[t*64 + n], __ATOMIC_ACQUIRE, __HIP_MEMORY_SCOPE_AGENT) < 4) {}
    }
    __syncthreads();
    {
        float* h1s   = (float*)smem;          // 64
        float* z1s   = h1s + 64;              // 512
        float* pla   = z1s + 512;             // 16*8
        float* pc    = pla + 128;             // 32
        float* la    = pc + 32;               // 16
        float* lu    = la + 16;               // 4
        float* ld2   = lu + 4;                // 2
        float* uvals = ld2 + 2;               // 4
        float* dp    = uvals + 4;             // 128
        float* sc    = dp + 128;              // 1
        int*   si    = (int*)(sc + 1);        // 4

        if (tid < CH) h1s[tid] = h1_buf[n*CH + tid];
        __syncthreads();
        int p = p_cur[n];
        size_t ob = ((size_t)t*N_ + n)*OUTW;

        const float* zmpp = zmp + (size_t)(n*NL + p)*HD;
        const float* zipp = zip + (size_t)(t*N_ + n)*HD;
        #pragma unroll
        for (int hh = 0; hh < 2; ++hh) {
            int h = tid + hh*256;
            float acc = zmpp[h] + zipp[h];
            #pragma unroll 8
            for (int c = 0; c < CH; ++c) acc += h1s[c]*zw[(E_ + c)*HD + h];
            float v = fmaxf(acc, 0.f);
            z1s[h] = v;
            out[ob + 146 + h] = v;
        }
        __syncthreads();

        if (tid < 128) {
            int a2 = tid >> 3, part = tid & 7;
            float acc = 0.f;
            const float* z0 = z1s + part*64;
            #pragma unroll 8
            for (int h = 0; h < 64; ++h) acc += z0[h]*aw[(part*64 + h)*A_ + a2];
            pla[a2*8 + part] = acc;
        } else if (tid < 160) {
            int part = tid - 128;
            float acc = 0.f;
            const float* z0 = z1s + part*16;
            #pragma unroll 8
            for (int h = 0; h < 16; ++h) acc += z0[h]*cw[part*16 + h];
            pc[part] = acc;
        } else if (tid < 164) {
            int e = tid - 160;
            float acc = ump[(n*NL + p)*NE + e] + uip[(t*N_ + n)*NE + e];
            #pragma unroll 8
            for (int c = 0; c < CH; ++c) acc += h1s[c]*uw[(E_ + c)*NE + e];
            lu[e] = acc;
        } else if (tid < 166) {
            int g = tid - 164;
            float acc = dmp[(n*NL + p)*2 + g] + dip[(t*N_ + n)*2 + g];
            #pragma unroll 8
            for (int c = 0; c < CH; ++c) acc += h1s[c]*dw[(E_ + c)*2 + g];
            ld2[g] = acc;
        }
        __syncthreads();
        if (tid < A_) {
            float acc = ab[tid];
            #pragma unroll
            for (int k = 0; k < 8; ++k) acc += pla[tid*8 + k];
            la[tid] = acc;
        } else if (tid == 24) {
            float acc = cb[0];
            #pragma unroll
            for (int k = 0; k < 32; ++k) acc += pc[k];
            sc[0] = acc;
        }
        __syncthreads();

        if (tid == 0) {
            float mx = la[0];
            #pragma unroll
            for (int k2 = 1; k2 < A_; ++k2) mx = fmaxf(mx, la[k2]);
            float pr[A_]; float sum = 0.f;
            #pragma unroll
            for (int k2 = 0; k2 < A_; ++k2) { pr[k2] = expf(la[k2]-mx); sum += pr[k2]; }
            const float* am = amask + ((size_t)t*N_ + n)*A_;
            float best = -1.f; int bi2 = 0;
            #pragma unroll
            for (int k2 = 0; k2 < A_; ++k2) {
                float v = pr[k2]/sum * am[k2];
                out[ob + 1 + k2] = v;
                if (v > best) { best = v; bi2 = k2; }
            }
            out[ob + 0] = (float)bi2;
        } else if (tid == 1) {
            float mx = fmaxf(fmaxf(lu[0], lu[1]), fmaxf(lu[2], lu[3]));
            float ev[NE]; float s0 = 0.f;
            #pragma unroll
            for (int e = 0; e < NE; ++e) { ev[e] = expf(lu[e]-mx); s0 += ev[e]; }
            #pragma unroll
            for (int e = 0; e < NE; ++e) uvals[e] = ev[e]/s0;
        } else if (tid == 2) {
            float mx = fmaxf(ld2[0], ld2[1]);
            float e0 = expf(ld2[0]-mx), e1 = expf(ld2[1]-mx);
            float s0 = e0 + e1;
            out[ob + 660] = e0/s0;
            out[ob + 661] = e1/s0;
            int dg = (ld2[1] > ld2[0]) ? 1 : 0;
            si[2] = dg;
            out[ob + 662] = (float)dg;
        }
        __syncthreads();
        if (tid < 128) {
            const float* Pp = Pall + ((size_t)(n*NL + p)*128 + tid)*NE;
            float v = Pp[0]*uvals[0] + Pp[1]*uvals[1] + Pp[2]*uvals[2] + Pp[3]*uvals[3];
            dp[tid] = v;
            out[ob + 18 + tid] = v;
        }
        __syncthreads();
        if (tid == 0) {
            int dsel;
            if (si[2] == 1) {
                float best = dp[0]; dsel = 0;
                for (int j2 = 1; j2 < 128; ++j2) if (dp[j2] > best) { best = dp[j2]; dsel = j2; }
            } else dsel = 64;
            int pn = p + dsel - 64;
            pn = pn < 0 ? 0 : (pn > 63 ? 63 : pn);
            si[3] = pn;
            p_cur[n] = pn;
            out[ob + 17]  = (float)dsel;
            out[ob + 658] = (float)pn;
            out[ob + 659] = sc[0];
        }
        __syncthreads();
        if (tid < E_) {
            mp_buf[n*E_ + tid] = M[(n*NL + si[3])*E_ + tid];
        }
    }
}

extern "C" void kernel_launch(void* const* d_in, const int* in_sizes, int n_in,
                              void* d_out, int out_size, void* d_ws, size_t ws_size,
                              hipStream_t stream) {
    (void)in_sizes; (void)n_in; (void)out_size; (void)ws_size;
    const int*   lines    = (const int*)  d_in[0];
    const float* obs      = (const float*)d_in[1];
    const float* invent   = (const float*)d_in[2];
    const int*   pa       = (const int*)  d_in[3];
    const float* amask    = (const float*)d_in[4];
    const int*   p0       = (const int*)  d_in[5];
    const float* emb_task = (const float*)d_in[6];
    const float* emb_low  = (const float*)d_in[7];
    const float* wi_f     = (const float*)d_in[8];
    const float* wh_f     = (const float*)d_in[9];
    const float* bi_f     = (const float*)d_in[10];
    const float* bh_f     = (const float*)d_in[11];
    const float* wi_b     = (const float*)d_in[12];
    const float* wh_b     = (const float*)d_in[13];
    const float* bi_b     = (const float*)d_in[14];
    const float* bh_b     = (const float*)d_in[15];
    const float* beta_w   = (const float*)d_in[16];
    const float* beta_b   = (const float*)d_in[17];
    const float* kernel_w = (const float*)d_in[18];
    const float* kernel_b = (const float*)d_in[19];
    const float* conv_b   = (const float*)d_in[20];
    const float* inv_w    = (const float*)d_in[21];
    const float* inv_b    = (const float*)d_in[22];
    const float* zw       = (const float*)d_in[23];
    const float* zb       = (const float*)d_in[24];
    const float* aw       = (const float*)d_in[25];
    const float* ab       = (const float*)d_in[26];
    const float* uw       = (const float*)d_in[27];
    const float* ub       = (const float*)d_in[28];
    const float* dw       = (const float*)d_in[29];
    const float* db       = (const float*)d_in[30];
    const float* cw       = (const float*)d_in[31];
    const float* cb       = (const float*)d_in[32];
    float* out = (float*)d_out;

    float* ws = (float*)d_ws;
    size_t off = 0;
    float* M        = ws + off; off += (size_t)N_*NL*E_;
    float* wiT4     = ws + off; off += 2*32*384*4;
    _Float16* WBpack = (_Float16*)(ws + off); off += (size_t)384*512/2;
    float* giM      = ws + off; off += (size_t)2*N_*NL*G3;
    float* Ball     = ws + off; off += (size_t)N_*NL*128*NE;
    float* Pall     = ws + off; off += (size_t)N_*NL*128*NE;
    float* inv_all  = ws + off; off += (size_t)T_*N_*RH;
    float* pa_all   = ws + off; off += (size_t)T_*N_*LE;
    float* kern_bufT= ws + off; off += (size_t)KCOLS*N_;
    float* h1_buf   = ws + off; off += (size_t)N_*CH;
    float* mp_buf   = ws + off; off += (size_t)N_*E_;
    float* zmp      = ws + off; off += (size_t)N_*NL*HD;
    float* zip      = ws + off; off += (size_t)T_*N_*HD;
    float* ump      = ws + off; off += (size_t)N_*NL*NE;
    float* dmp      = ws + off; off += (size_t)N_*NL*2;
    float* uip      = ws + off; off += (size_t)T_*N_*NE;
    float* dip      = ws + off; off += (size_t)T_*N_*2;
    int*   p_cur    = (int*)(ws + off); off += 64;
    int*   cnt      = (int*)(ws + off); off += 32 + 32*64;
    int*   cnt_kern = cnt;
    int*   cnt_conv = cnt + 32;

    k_prep_M<<<N_*NL, 128, 0, stream>>>(lines, emb_task, M);
    k_zero<<<9, 256, 0, stream>>>(cnt);
    k_prep_T4<<<768, 128, 0, stream>>>(wi_f, wi_b, wiT4);
    k_packW<<<384, 64, 0, stream>>>(wh_f, wh_b, WBpack);
    k_prep_misc<<<N_, 128, 0, stream>>>(p0, M, p_cur, mp_buf);
    k_prep_invpa<<<T_*N_, 64, 0, stream>>>(invent, inv_w, inv_b, pa, emb_low, inv_all, pa_all);
    k_giM<<<dim3(8, N_, 2), 384, 0, stream>>>(M, wiT4, bi_f, bi_b, giM);
    k_gru<<<dim3(2, N_, 2), 256, 0, stream>>>(giM, WBpack, bh_f, bh_b, beta_w, beta_b, Ball);
    k_P<<<N_*NL, 64, 0, stream>>>(Ball, Pall);
    k_zmp<<<dim3(2, 128), 256, 0, stream>>>(M, zw, zmp);
    k_ip<<<dim3(2, 64), 256, 0, stream>>>(inv_all, pa_all, zw, zb, zip);
    k_mpsmall<<<64, 256, 0, stream>>>(M, uw, dw, ump, dmp);
    k_ipsmall<<<32, 256, 0, stream>>>(inv_all, pa_all, uw, ub, dw, db, uip, dip);

    for (int t = 0; t < T_; ++t) {
        k_step<<<256, 256, 0, stream>>>(obs, kernel_w, kernel_b, conv_b,
                                        kern_bufT, h1_buf,
                                        zmp, zip, ump, uip, dmp, dip,
                                        zw, aw, ab, uw, dw, cw, cb,
                                        amask, Pall, M, mp_buf, p_cur, out,
                                        cnt_kern, cnt_conv, t);
    }
}

// Round 7
// 2427.485 us; speedup vs baseline: 1.5978x; 1.5978x over previous
//
#include <hip/hip_runtime.h>
#include <math.h>

#define T_   32
#define N_   64
#define NL   64
#define E_   128
#define G3   384   // 3*E
#define NE   4
#define CH   64
#define D_   16
#define HW   16
#define RH   64
#define LE   64
#define HD   512
#define A_   16
#define INVN 32
#define KCOLS 9216 // CH*D_*3*3
#define OUTW 663

typedef _Float16 half8 __attribute__((ext_vector_type(8)));
typedef float floatx4 __attribute__((ext_vector_type(4)));

__device__ __forceinline__ float fsig(float x)  { return __builtin_amdgcn_rcpf(1.f + __expf(-x)); }
__device__ __forceinline__ float ftanh(float x) { return 1.f - 2.f*__builtin_amdgcn_rcpf(1.f + __expf(2.f*x)); }

// ---------------- merged prep 1: M, wiT4, WBpack, invpa, cnt-zero ----------------
__global__ __launch_bounds__(256) void k_prep1(
    const int* lines, const float* emb_task, float* M,
    const float* wif, const float* wib, float* wiT4,
    const float* whf, const float* whb, _Float16* WBpack,
    const float* inv, const float* inv_w, const float* inv_b,
    const int* pa, const float* emb_lower, float* inv_all, float* pa_all,
    int* cnt) {
    int b = blockIdx.x, tid = threadIdx.x;
    if (b < 1024) {                    // M: emb-bag sum
        #pragma unroll
        for (int r = 0; r < 2; ++r) {
            int idx = b*512 + r*256 + tid;
            int nl = idx >> 7, i = idx & 127;
            const int* ln = lines + nl*4;
            float s = 0.f;
            #pragma unroll
            for (int t = 0; t < 4; ++t) s += emb_task[ln[t]*E_ + i];
            M[nl*E_ + i] = s;
        }
    } else if (b < 1408) {             // wiT4 repack
        int ob = (b - 1024)*2 + (tid >> 7);
        int g = ob % 384, dir = ob / 384;
        int k = tid & 127;
        const float* wi = dir ? wib : wif;
        int dst = ((dir*32 + (k>>2))*384 + g)*4 + (k&3);
        wiT4[dst] = wi[g*128 + k];
    } else if (b < 1504) {             // WBpack fp16 hi/lo fragments
        int ob = (b - 1408)*4 + (tid >> 6);
        int lane = tid & 63;
        int nt = ob % 6; int rest = ob / 6;
        int term = rest % 2; rest /= 2;
        int kt = rest % 4; rest /= 4;
        int w = rest % 4; int dir = rest / 4;
        const float* wh = dir ? whb : whf;
        int gt = nt >> 1, isub = nt & 1;
        int g  = gt*128 + w*32 + isub*16 + (lane & 15);
        int k0 = kt*32 + (lane >> 4)*8;
        _Float16* dst = WBpack + (size_t)ob*512 + lane*8;
        #pragma unroll
        for (int e = 0; e < 8; ++e) {
            float v = wh[g*128 + k0 + e];
            _Float16 hi = (_Float16)v;
            dst[e] = (term == 0) ? hi : (_Float16)(v - (float)hi);
        }
    } else if (b < 2016) {             // inv relu + pa emb-bag
        int tn = (b - 1504)*4 + (tid >> 6);
        int r = tid & 63;
        const float* iv = inv + tn*INVN;
        float acc = inv_b[r];
        #pragma unroll
        for (int i = 0; i < INVN; ++i) acc += iv[i]*inv_w[i*RH + r];
        inv_all[tn*RH + r] = fmaxf(acc, 0.f);
        const int* pp = pa + tn*4;
        float s = 0.f;
        #pragma unroll
        for (int j = 0; j < 4; ++j) s += emb_lower[pp[j]*LE + r];
        pa_all[tn*LE + r] = s;
    } else {                           // zero rendezvous counters (32768 ints)
        cnt[(b - 2016)*256 + tid] = 0;
    }
}

// ---------------- merged prep 2: zmp, zip, ump/dmp, uip/dip, p0/mp init ----------------
__global__ __launch_bounds__(256) void k_prep2(
    const float* M, const float* inv_all, const float* pa_all,
    const float* zw, const float* zb,
    const float* uw, const float* ub, const float* dw, const float* db,
    const int* p0, int* p_cur, float* mp_buf,
    float* zmp, float* zip, float* ump, float* dmp, float* uip, float* dip) {
    int b = blockIdx.x, tid = threadIdx.x;
    if (b < 256) {                     // zmp = M @ zw[0:128]
        int cb = b & 1, rb = b >> 1;
        __shared__ float At[32][E_];
        for (int idx = tid; idx < 32*E_; idx += 256) {
            int r = idx >> 7, k = idx & 127;
            At[r][k] = M[(rb*32 + r)*E_ + k];
        }
        __syncthreads();
        float acc[32];
        #pragma unroll
        for (int r = 0; r < 32; ++r) acc[r] = 0.f;
        int col = cb*256 + tid;
        #pragma unroll 4
        for (int k = 0; k < E_; ++k) {
            float w = zw[k*HD + col];
            #pragma unroll
            for (int r = 0; r < 32; ++r) acc[r] += At[r][k]*w;
        }
        #pragma unroll
        for (int r = 0; r < 32; ++r)
            zmp[(size_t)(rb*32 + r)*HD + col] = acc[r];
    } else if (b < 384) {              // zip = [inv|pa] @ zw[192:320] + zb
        int b2 = b - 256;
        int cb = b2 & 1, rb = b2 >> 1;
        __shared__ float At2[32][E_];
        for (int idx = tid; idx < 32*E_; idx += 256) {
            int r = idx >> 7, k = idx & 127;
            int row = rb*32 + r;
            At2[r][k] = (k < 64) ? inv_all[row*RH + k] : pa_all[row*LE + (k - 64)];
        }
        __syncthreads();
        float acc[32];
        #pragma unroll
        for (int r = 0; r < 32; ++r) acc[r] = 0.f;
        int col = cb*256 + tid;
        #pragma unroll 4
        for (int k = 0; k < E_; ++k) {
            float w = zw[(192 + k)*HD + col];
            #pragma unroll
            for (int r = 0; r < 32; ++r) acc[r] += At2[r][k]*w;
        }
        float bb = zb[col];
        #pragma unroll
        for (int r = 0; r < 32; ++r)
            zip[(size_t)(rb*32 + r)*HD + col] = acc[r] + bb;
    } else if (b < 448) {              // ump/dmp from M
        int wg = b - 384;
        __shared__ float Mt[64][E_];
        for (int idx = tid; idx < 64*E_; idx += 256)
            ((float*)Mt)[idx] = M[(size_t)wg*64*E_ + idx];
        __syncthreads();
        int r = tid >> 2, q = tid & 3;
        float au = 0.f, ad = 0.f;
        #pragma unroll 4
        for (int k = 0; k < E_; ++k) {
            float m = Mt[r][k];
            au += m*uw[k*NE + q];
            if (q < 2) ad += m*dw[k*2 + q];
        }
        int row = wg*64 + r;
        ump[row*NE + q] = au;
        if (q < 2) dmp[row*2 + q] = ad;
    } else if (b < 480) {              // uip/dip from inv/pa
        int wg = b - 448;
        __shared__ float At3[64][E_];
        for (int idx = tid; idx < 64*E_; idx += 256) {
            int r = idx >> 7, k = idx & 127;
            int row = wg*64 + r;
            At3[r][k] = (k < 64) ? inv_all[row*RH + k] : pa_all[row*LE + (k - 64)];
        }
        __syncthreads();
        int r = tid >> 2, q = tid & 3;
        float au = ub[q], ad = (q < 2) ? db[q] : 0.f;
        #pragma unroll 4
        for (int k = 0; k < E_; ++k) {
            float v = At3[r][k];
            au += v*uw[(192 + k)*NE + q];
            if (q < 2) ad += v*dw[(192 + k)*2 + q];
        }
        int row = wg*64 + r;
        uip[row*NE + q] = au;
        if (q < 2) dip[row*2 + q] = ad;
    } else {                           // p0 -> p_cur, mp init
        int n = (b - 480)*2 + (tid >> 7);
        int i = tid & 127;
        int p = p0[n];
        if (i == 0) p_cur[n] = p;
        mp_buf[n*E_ + i] = M[(n*NL + p)*E_ + i];
    }
}

// giM[dir][n][l][g] = M[n][l] . wi[g] + bi[g]
__global__ __launch_bounds__(384) void k_giM(const float* M, const float* wiT4,
                                             const float* bif, const float* bib, float* giM) {
    int lblk = blockIdx.x, n = blockIdx.y, dir = blockIdx.z;
    int g = threadIdx.x;
    __shared__ float Ml[8][E_];
    for (int idx = g; idx < 8*E_; idx += 384) {
        int r = idx >> 7, k = idx & 127;
        Ml[r][k] = M[(n*NL + lblk*8 + r)*E_ + k];
    }
    __syncthreads();
    float acc[8];
    #pragma unroll
    for (int r = 0; r < 8; ++r) acc[r] = 0.f;
    const float4* W = (const float4*)(wiT4) + dir*32*384;
    for (int kq = 0; kq < 32; ++kq) {
        float4 w = W[kq*384 + g];
        #pragma unroll
        for (int r = 0; r < 8; ++r) {
            float4 h = *(const float4*)&Ml[r][kq*4];
            acc[r] += w.x*h.x + w.y*h.y + w.z*h.z + w.w*h.w;
        }
    }
    float bi = dir ? bib[g] : bif[g];
    #pragma unroll
    for (int r = 0; r < 8; ++r)
        giM[((dir*N_ + n)*NL + lblk*8 + r)*G3 + g] = acc[r] + bi;
}

// ---------------- MFMA GRU: grid (pblk 4, n 64, dir 2) = 512 wgs, 16 seqs/wg ----------------
__global__ __launch_bounds__(256, 2) void k_gru(const float* giM, const _Float16* WBpack,
                                                const float* bhf, const float* bhb,
                                                const float* beta_w, const float* beta_b,
                                                float* Ball) {
    int pblk = blockIdx.x, n = blockIdx.y, dir = blockIdx.z;
    int tid = threadIdx.x;
    int w = tid >> 6;
    int lane = tid & 63;
    int quad = lane >> 4;
    int col  = lane & 15;

    __shared__ _Float16 Hhi[16*136];
    __shared__ _Float16 Hlo[16*136];
    __shared__ float    Hf[16*132];
    __shared__ float    bwT[4*132];
    for (int idx = tid; idx < 16*136; idx += 256) { Hhi[idx] = (_Float16)0.f; Hlo[idx] = (_Float16)0.f; }
    for (int idx = tid; idx < 16*132; idx += 256) Hf[idx] = 0.f;
    for (int idx = tid; idx < 512; idx += 256) { int k = idx >> 2, e = idx & 3; bwT[e*132 + k] = beta_w[k*NE + e]; }

    half8 WB[48];
    const half8* wsrc = (const half8*)(WBpack) + ((size_t)(dir*4 + w)*4)*12*64;
    #pragma unroll
    for (int f = 0; f < 48; ++f) WB[f] = wsrc[(size_t)f*64 + lane];

    const float* bh = dir ? bhb : bhf;
    float bhv[6];
    #pragma unroll
    for (int gt2 = 0; gt2 < 3; ++gt2) {
        bhv[gt2*2+0] = bh[gt2*128 + w*32 + col];
        bhv[gt2*2+1] = bh[gt2*128 + w*32 + col + 16];
    }
    const float* giBase = giM + (size_t)(dir*N_ + n)*NL*G3;

    int bseq = tid >> 4, bsub = tid & 15, bee = bsub & 3, bpart = bsub >> 2;
    float bbias = beta_b[bee];
    __syncthreads();

    for (int j = 0; j < NL; ++j) {
        floatx4 C[6];   // nt = gt*2 + isub (gt: 0=r,1=z,2=n)
        #pragma unroll
        for (int reg = 0; reg < 4; ++reg) {
            int seq = quad*4 + reg;
            int p = pblk*16 + seq;
            int l = dir ? ((p + 63 - j) & 63) : ((p + j) & 63);
            const float* gl = giBase + l*G3 + w*32 + col;
            #pragma unroll
            for (int gt2 = 0; gt2 < 2; ++gt2)
                #pragma unroll
                for (int isub = 0; isub < 2; ++isub)
                    C[gt2*2 + isub][reg] = gl[gt2*128 + isub*16] + bhv[gt2*2+isub];
            #pragma unroll
            for (int isub = 0; isub < 2; ++isub)
                C[4 + isub][reg] = bhv[4+isub];
        }
        #pragma unroll
        for (int kt = 0; kt < 4; ++kt) {
            int off = col*136 + kt*32 + quad*8;
            half8 ahi = *(const half8*)&Hhi[off];
            half8 alo = *(const half8*)&Hlo[off];
            #pragma unroll
            for (int nt = 0; nt < 6; ++nt) {
                half8 bhi2 = WB[kt*12 + nt];
                half8 blo2 = WB[kt*12 + 6 + nt];
                C[nt] = __builtin_amdgcn_mfma_f32_16x16x32_f16(ahi, bhi2, C[nt], 0,0,0);
                C[nt] = __builtin_amdgcn_mfma_f32_16x16x32_f16(alo, bhi2, C[nt], 0,0,0);
                C[nt] = __builtin_amdgcn_mfma_f32_16x16x32_f16(ahi, blo2, C[nt], 0,0,0);
            }
        }
        __syncthreads();

        #pragma unroll
        for (int reg = 0; reg < 4; ++reg) {
            int seq = quad*4 + reg;
            int p = pblk*16 + seq;
            int l = dir ? ((p + 63 - j) & 63) : ((p + j) & 63);
            const float* gl = giBase + l*G3 + 256 + w*32 + col;
            #pragma unroll
            for (int isub = 0; isub < 2; ++isub) {
                int i = w*32 + isub*16 + col;
                float r  = fsig(C[isub][reg]);
                float z  = fsig(C[2 + isub][reg]);
                float nn = ftanh(gl[isub*16] + r*C[4 + isub][reg]);
                float hold = Hf[seq*132 + i];
                float hnew = (1.f - z)*nn + z*hold;
                _Float16 hi = (_Float16)hnew;
                _Float16 lo = (_Float16)(hnew - (float)hi);
                Hf[seq*132 + i] = hnew;
                Hhi[seq*136 + i] = hi;
                Hlo[seq*136 + i] = lo;
            }
        }
        __syncthreads();

        // beta head: 16 seqs x 4 e x 4 strided k-parts
        {
            float acc = 0.f;
            const float* hrow = &Hf[bseq*132];
            const float* brow = &bwT[bee*132];
            #pragma unroll 8
            for (int kk = 0; kk < 32; ++kk) {
                int k2 = bpart + 4*kk;
                acc += hrow[k2]*brow[k2];
            }
            acc += __shfl_xor(acc, 4);
            acc += __shfl_xor(acc, 8);
            if (bpart == 0) {
                float bval = fsig(acc + bbias);
                int p = pblk*16 + bseq;
                Ball[((n*NL + p)*128 + 2*j + dir)*NE + bee] = bval;
            }
        }
    }
}

// stick-breaking -> reordered P_final[n][p][j][e]
__global__ __launch_bounds__(64) void k_P(const float* Ball, float* Pall) {
    int np = blockIdx.x;
    int tid = threadIdx.x;
    __shared__ float B[128][NE];
    __shared__ float Pf[128][NE];
    const float* src = Ball + np*128*NE;
    for (int idx = tid; idx < 128*NE; idx += 64) ((float*)B)[idx] = src[idx];
    __syncthreads();
    if (tid < NE) {
        int e = tid;
        float c = 1.f;
        for (int j2 = 0; j2 < 128; ++j2) {
            float bz = (j2 == 0 || j2 == 127) ? 0.f : B[j2][e];
            float bf = (j2 == 127) ? 1.f : bz;
            Pf[j2][e] = bf * c;
            c *= (1.f - bz);
        }
    }
    __syncthreads();
    float* dst = Pall + np*128*NE;
    for (int idx = tid; idx < 128*NE; idx += 64) {
        int j = idx >> 2, e = idx & 3;
        int jf = (j < 64) ? (2*(63 - j) + 1) : (2*(j - 64));
        dst[idx] = Pf[jf][e];
    }
}

// ---------------- one dispatch per step ----------------
// 256 wgs (q = wg&3, n = wg>>2), 256 thr. Self-sufficient kern quarter (LDS) + conv
// quarter; only a 4-wide h1 rendezvous (64 B) before heads in the q==0 wg.
__global__ __launch_bounds__(256) void k_step(
    const float* obs, const float* kernel_w, const float* kernel_b, const float* conv_bias,
    float* h1_buf,
    const float* zmp, const float* zip,
    const float* ump, const float* uip, const float* dmp, const float* dip,
    const float* zw, const float* aw, const float* ab,
    const float* uw, const float* dw, const float* cw, const float* cb,
    const float* amask, const float* Pall, const float* M,
    float* mp_buf, int* p_cur, float* out,
    int* cnt, int t) {

    int wg = blockIdx.x, tid = threadIdx.x;
    int q = wg & 3, n = wg >> 2;

    __shared__ float ms[128];
    __shared__ float kl[2304];
    __shared__ __align__(16) float obs_l[D_*HW*20];   // 20480 B; reused by heads
    __shared__ float h1s[CH];

    // stage obs + mp
    const float4* op4 = (const float4*)(obs + (size_t)(t*N_ + n)*D_*HW*HW);
    #pragma unroll
    for (int k = 0; k < 4; ++k) {
        int idx = tid + k*256;
        int d = idx >> 6, rem = idx & 63;
        int y = rem >> 2, xq = rem & 3;
        *(float4*)&obs_l[d*320 + y*20 + xq*4] = op4[idx];
    }
    if (tid < 128) ms[tid] = mp_buf[n*E_ + tid];
    __syncthreads();

    // ---- kern quarter GEMM (output stays in LDS) ----
    {
        const float* kwp = kernel_w + q*2304 + tid;
        float acc[9];
        #pragma unroll
        for (int jj = 0; jj < 9; ++jj) acc[jj] = kernel_b[q*2304 + jj*256 + tid];
        #pragma unroll 4
        for (int k = 0; k < 128; ++k) {
            float m = ms[k];
            const float* row = kwp + (size_t)k*KCOLS;
            #pragma unroll
            for (int jj = 0; jj < 9; ++jj) acc[jj] = fmaf(m, row[jj*256], acc[jj]);
        }
        #pragma unroll
        for (int jj = 0; jj < 9; ++jj) kl[jj*256 + tid] = acc[jj];
    }
    __syncthreads();

    // ---- conv quarter ----
    {
        int c = tid >> 4, y = tid & 15;
        float acc[16];
        #pragma unroll
        for (int x = 0; x < 16; ++x) acc[x] = 0.f;
        for (int d = 0; d < D_; ++d) {
            const float* kd = &kl[c*144 + d*9];
            #pragma unroll
            for (int ky = 0; ky < 3; ++ky) {
                int yy = y + ky - 1;
                if (yy < 0 || yy >= HW) continue;
                const float4* rs = (const float4*)&obs_l[(d*16 + yy)*20];
                float4 r0 = rs[0], r1 = rs[1], r2 = rs[2], r3 = rs[3];
                float row[18];
                row[0] = 0.f; row[17] = 0.f;
                row[1]=r0.x; row[2]=r0.y; row[3]=r0.z; row[4]=r0.w;
                row[5]=r1.x; row[6]=r1.y; row[7]=r1.z; row[8]=r1.w;
                row[9]=r2.x; row[10]=r2.y; row[11]=r2.z; row[12]=r2.w;
                row[13]=r3.x; row[14]=r3.y; row[15]=r3.z; row[16]=r3.w;
                float k0 = kd[ky*3], k1 = kd[ky*3+1], k2 = kd[ky*3+2];
                #pragma unroll
                for (int x = 0; x < 16; ++x)
                    acc[x] += row[x]*k0 + row[x+1]*k1 + row[x+2]*k2;
            }
        }
        float bc = conv_bias[q*16 + c];
        float psum = 0.f;
        #pragma unroll
        for (int x = 0; x < 16; ++x) psum += fmaxf(acc[x] + bc, 0.f);
        psum += __shfl_xor(psum, 1);
        psum += __shfl_xor(psum, 2);
        psum += __shfl_xor(psum, 4);
        psum += __shfl_xor(psum, 8);
        if (y == 0) {
            if (q == 0) h1s[c] = psum;
            else        h1_buf[n*CH + q*16 + c] = psum;
        }
    }
    __threadfence();
    __syncthreads();

    if (q != 0) {
        if (tid == 0)
            __hip_atomic_fetch_add(&cnt[(t*64 + n)*16], 1, __ATOMIC_RELEASE, __HIP_MEMORY_SCOPE_AGENT);
        return;
    }

    // ---- 4-wide rendezvous: relaxed spin + single acquire ----
    if (tid == 0) {
        volatile int* flag = &cnt[(t*64 + n)*16];
        while (__hip_atomic_load((int*)flag, __ATOMIC_RELAXED, __HIP_MEMORY_SCOPE_AGENT) < 3)
            __builtin_amdgcn_s_sleep(1);
        (void)__hip_atomic_load((int*)flag, __ATOMIC_ACQUIRE, __HIP_MEMORY_SCOPE_AGENT);
    }
    __syncthreads();
    if (tid < 48) h1s[16 + tid] = h1_buf[n*CH + 16 + tid];
    __syncthreads();

    // ---- heads ----
    {
        float* hb    = obs_l;                 // reuse conv scratch
        float* z1s   = hb;                    // 512
        float* pla   = z1s + 512;             // 128
        float* pc    = pla + 128;             // 32
        float* la    = pc + 32;               // 16
        float* lu    = la + 16;               // 4
        float* ld2   = lu + 4;                // 2
        float* uvals = ld2 + 2;               // 4
        float* dp    = uvals + 4;             // 128
        float* sc    = dp + 128;              // 1
        int*   si    = (int*)(sc + 1);        // 4

        if (tid == 0) si[0] = p_cur[n];
        __syncthreads();
        int p = si[0];
        size_t ob = ((size_t)t*N_ + n)*OUTW;

        const float* zmpp = zmp + (size_t)(n*NL + p)*HD;
        const float* zipp = zip + (size_t)(t*N_ + n)*HD;
        #pragma unroll
        for (int hh = 0; hh < 2; ++hh) {
            int h = tid + hh*256;
            float acc = zmpp[h] + zipp[h];
            #pragma unroll 8
            for (int c = 0; c < CH; ++c) acc += h1s[c]*zw[(E_ + c)*HD + h];
            float v = fmaxf(acc, 0.f);
            z1s[h] = v;
            out[ob + 146 + h] = v;
        }
        __syncthreads();

        if (tid < 128) {
            int a2 = tid >> 3, part = tid & 7;
            float acc = 0.f;
            const float* z0 = z1s + part*64;
            #pragma unroll 8
            for (int h = 0; h < 64; ++h) acc += z0[h]*aw[(part*64 + h)*A_ + a2];
            pla[a2*8 + part] = acc;
        } else if (tid < 160) {
            int part = tid - 128;
            float acc = 0.f;
            const float* z0 = z1s + part*16;
            #pragma unroll 8
            for (int h = 0; h < 16; ++h) acc += z0[h]*cw[part*16 + h];
            pc[part] = acc;
        } else if (tid < 164) {
            int e = tid - 160;
            float acc = ump[(n*NL + p)*NE + e] + uip[(t*N_ + n)*NE + e];
            #pragma unroll 8
            for (int c = 0; c < CH; ++c) acc += h1s[c]*uw[(E_ + c)*NE + e];
            lu[e] = acc;
        } else if (tid < 166) {
            int g = tid - 164;
            float acc = dmp[(n*NL + p)*2 + g] + dip[(t*N_ + n)*2 + g];
            #pragma unroll 8
            for (int c = 0; c < CH; ++c) acc += h1s[c]*dw[(E_ + c)*2 + g];
            ld2[g] = acc;
        }
        __syncthreads();
        if (tid < A_) {
            float acc = ab[tid];
            #pragma unroll
            for (int k = 0; k < 8; ++k) acc += pla[tid*8 + k];
            la[tid] = acc;
        } else if (tid == 24) {
            float acc = cb[0];
            #pragma unroll
            for (int k = 0; k < 32; ++k) acc += pc[k];
            sc[0] = acc;
        }
        __syncthreads();

        if (tid == 0) {
            float mx = la[0];
            #pragma unroll
            for (int k2 = 1; k2 < A_; ++k2) mx = fmaxf(mx, la[k2]);
            float pr[A_]; float sum = 0.f;
            #pragma unroll
            for (int k2 = 0; k2 < A_; ++k2) { pr[k2] = expf(la[k2]-mx); sum += pr[k2]; }
            const float* am = amask + ((size_t)t*N_ + n)*A_;
            float best = -1.f; int bi2 = 0;
            #pragma unroll
            for (int k2 = 0; k2 < A_; ++k2) {
                float v = pr[k2]/sum * am[k2];
                out[ob + 1 + k2] = v;
                if (v > best) { best = v; bi2 = k2; }
            }
            out[ob + 0] = (float)bi2;
        } else if (tid == 1) {
            float mx = fmaxf(fmaxf(lu[0], lu[1]), fmaxf(lu[2], lu[3]));
            float ev[NE]; float s0 = 0.f;
            #pragma unroll
            for (int e = 0; e < NE; ++e) { ev[e] = expf(lu[e]-mx); s0 += ev[e]; }
            #pragma unroll
            for (int e = 0; e < NE; ++e) uvals[e] = ev[e]/s0;
        } else if (tid == 2) {
            float mx = fmaxf(ld2[0], ld2[1]);
            float e0 = expf(ld2[0]-mx), e1 = expf(ld2[1]-mx);
            float s0 = e0 + e1;
            out[ob + 660] = e0/s0;
            out[ob + 661] = e1/s0;
            int dg = (ld2[1] > ld2[0]) ? 1 : 0;
            si[2] = dg;
            out[ob + 662] = (float)dg;
        }
        __syncthreads();
        if (tid < 128) {
            const float* Pp = Pall + ((size_t)(n*NL + p)*128 + tid)*NE;
            float v = Pp[0]*uvals[0] + Pp[1]*uvals[1] + Pp[2]*uvals[2] + Pp[3]*uvals[3];
            dp[tid] = v;
            out[ob + 18 + tid] = v;
        }
        __syncthreads();
        if (tid == 0) {
            int dsel;
            if (si[2] == 1) {
                float best = dp[0]; dsel = 0;
                for (int j2 = 1; j2 < 128; ++j2) if (dp[j2] > best) { best = dp[j2]; dsel = j2; }
            } else dsel = 64;
            int pn = p + dsel - 64;
            pn = pn < 0 ? 0 : (pn > 63 ? 63 : pn);
            si[3] = pn;
            p_cur[n] = pn;
            out[ob + 17]  = (float)dsel;
            out[ob + 658] = (float)pn;
            out[ob + 659] = sc[0];
        }
        __syncthreads();
        if (tid < E_) {
            mp_buf[n*E_ + tid] = M[(n*NL + si[3])*E_ + tid];
        }
    }
}

extern "C" void kernel_launch(void* const* d_in, const int* in_sizes, int n_in,
                              void* d_out, int out_size, void* d_ws, size_t ws_size,
                              hipStream_t stream) {
    (void)in_sizes; (void)n_in; (void)out_size; (void)ws_size;
    const int*   lines    = (const int*)  d_in[0];
    const float* obs      = (const float*)d_in[1];
    const float* invent   = (const float*)d_in[2];
    const int*   pa       = (const int*)  d_in[3];
    const float* amask    = (const float*)d_in[4];
    const int*   p0       = (const int*)  d_in[5];
    const float* emb_task = (const float*)d_in[6];
    const float* emb_low  = (const float*)d_in[7];
    const float* wi_f     = (const float*)d_in[8];
    const float* wh_f     = (const float*)d_in[9];
    const float* bi_f     = (const float*)d_in[10];
    const float* bh_f     = (const float*)d_in[11];
    const float* wi_b     = (const float*)d_in[12];
    const float* wh_b     = (const float*)d_in[13];
    const float* bi_b     = (const float*)d_in[14];
    const float* bh_b     = (const float*)d_in[15];
    const float* beta_w   = (const float*)d_in[16];
    const float* beta_b   = (const float*)d_in[17];
    const float* kernel_w = (const float*)d_in[18];
    const float* kernel_b = (const float*)d_in[19];
    const float* conv_b   = (const float*)d_in[20];
    const float* inv_w    = (const float*)d_in[21];
    const float* inv_b    = (const float*)d_in[22];
    const float* zw       = (const float*)d_in[23];
    const float* zb       = (const float*)d_in[24];
    const float* aw       = (const float*)d_in[25];
    const float* ab       = (const float*)d_in[26];
    const float* uw       = (const float*)d_in[27];
    const float* ub       = (const float*)d_in[28];
    const float* dw       = (const float*)d_in[29];
    const float* db       = (const float*)d_in[30];
    const float* cw       = (const float*)d_in[31];
    const float* cb       = (const float*)d_in[32];
    float* out = (float*)d_out;

    float* ws = (float*)d_ws;
    size_t off = 0;
    float* M        = ws + off; off += (size_t)N_*NL*E_;
    float* wiT4     = ws + off; off += 2*32*384*4;
    _Float16* WBpack = (_Float16*)(ws + off); off += (size_t)384*512/2;
    float* giM      = ws + off; off += (size_t)2*N_*NL*G3;
    float* Ball     = ws + off; off += (size_t)N_*NL*128*NE;
    float* Pall     = ws + off; off += (size_t)N_*NL*128*NE;
    float* inv_all  = ws + off; off += (size_t)T_*N_*RH;
    float* pa_all   = ws + off; off += (size_t)T_*N_*LE;
    float* h1_buf   = ws + off; off += (size_t)N_*CH;
    float* mp_buf   = ws + off; off += (size_t)N_*E_;
    float* zmp      = ws + off; off += (size_t)N_*NL*HD;
    float* zip      = ws + off; off += (size_t)T_*N_*HD;
    float* ump      = ws + off; off += (size_t)N_*NL*NE;
    float* dmp      = ws + off; off += (size_t)N_*NL*2;
    float* uip      = ws + off; off += (size_t)T_*N_*NE;
    float* dip      = ws + off; off += (size_t)T_*N_*2;
    int*   p_cur    = (int*)(ws + off); off += 64;
    int*   cnt      = (int*)(ws + off); off += 32*64*16;   // padded rendezvous counters

    k_prep1<<<2144, 256, 0, stream>>>(lines, emb_task, M, wi_f, wi_b, wiT4,
                                      wh_f, wh_b, WBpack,
                                      invent, inv_w, inv_b, pa, emb_low, inv_all, pa_all, cnt);
    k_prep2<<<512, 256, 0, stream>>>(M, inv_all, pa_all, zw, zb, uw, ub, dw, db,
                                     p0, p_cur, mp_buf, zmp, zip, ump, dmp, uip, dip);
    k_giM<<<dim3(8, N_, 2), 384, 0, stream>>>(M, wiT4, bi_f, bi_b, giM);
    k_gru<<<dim3(4, N_, 2), 256, 0, stream>>>(giM, WBpack, bh_f, bh_b, beta_w, beta_b, Ball);
    k_P<<<N_*NL, 64, 0, stream>>>(Ball, Pall);

    for (int t = 0; t < T_; ++t) {
        k_step<<<256, 256, 0, stream>>>(obs, kernel_w, kernel_b, conv_b, h1_buf,
                                        zmp, zip, ump, uip, dmp, dip,
                                        zw, aw, ab, uw, dw, cw, cb,
                                        amask, Pall, M, mp_buf, p_cur, out,
                                        cnt, t);
    }
}

// Round 8
// 1804.203 us; speedup vs baseline: 2.1498x; 1.3455x over previous
//
#include <hip/hip_runtime.h>
#include <math.h>

#define T_   32
#define N_   64
#define NL   64
#define E_   128
#define G3   384   // 3*E
#define NE   4
#define CH   64
#define D_   16
#define HW   16
#define RH   64
#define LE   64
#define HD   512
#define A_   16
#define INVN 32
#define KCOLS 9216 // CH*D_*3*3
#define OUTW 663

typedef _Float16 half8 __attribute__((ext_vector_type(8)));
typedef float floatx4 __attribute__((ext_vector_type(4)));

__device__ __forceinline__ float fsig(float x)  { return __builtin_amdgcn_rcpf(1.f + __expf(-x)); }
__device__ __forceinline__ float ftanh(float x) { return 1.f - 2.f*__builtin_amdgcn_rcpf(1.f + __expf(2.f*x)); }

// ---------------- merged prep 1: M, wiT4, WBpack, invpa, flags-zero ----------------
__global__ __launch_bounds__(256) void k_prep1(
    const int* lines, const float* emb_task, float* M,
    const float* wif, const float* wib, float* wiT4,
    const float* whf, const float* whb, _Float16* WBpack,
    const float* inv, const float* inv_w, const float* inv_b,
    const int* pa, const float* emb_lower, float* inv_all, float* pa_all,
    int* flags) {
    int b = blockIdx.x, tid = threadIdx.x;
    if (b < 1024) {                    // M: emb-bag sum
        #pragma unroll
        for (int r = 0; r < 2; ++r) {
            int idx = b*512 + r*256 + tid;
            int nl = idx >> 7, i = idx & 127;
            const int* ln = lines + nl*4;
            float s = 0.f;
            #pragma unroll
            for (int t = 0; t < 4; ++t) s += emb_task[ln[t]*E_ + i];
            M[nl*E_ + i] = s;
        }
    } else if (b < 1408) {             // wiT4 repack
        int ob = (b - 1024)*2 + (tid >> 7);
        int g = ob % 384, dir = ob / 384;
        int k = tid & 127;
        const float* wi = dir ? wib : wif;
        int dst = ((dir*32 + (k>>2))*384 + g)*4 + (k&3);
        wiT4[dst] = wi[g*128 + k];
    } else if (b < 1504) {             // WBpack fp16 hi/lo fragments
        int ob = (b - 1408)*4 + (tid >> 6);
        int lane = tid & 63;
        int nt = ob % 6; int rest = ob / 6;
        int term = rest % 2; rest /= 2;
        int kt = rest % 4; rest /= 4;
        int w = rest % 4; int dir = rest / 4;
        const float* wh = dir ? whb : whf;
        int gt = nt >> 1, isub = nt & 1;
        int g  = gt*128 + w*32 + isub*16 + (lane & 15);
        int k0 = kt*32 + (lane >> 4)*8;
        _Float16* dst = WBpack + (size_t)ob*512 + lane*8;
        #pragma unroll
        for (int e = 0; e < 8; ++e) {
            float v = wh[g*128 + k0 + e];
            _Float16 hi = (_Float16)v;
            dst[e] = (term == 0) ? hi : (_Float16)(v - (float)hi);
        }
    } else if (b < 2016) {             // inv relu + pa emb-bag
        int tn = (b - 1504)*4 + (tid >> 6);
        int r = tid & 63;
        const float* iv = inv + tn*INVN;
        float acc = inv_b[r];
        #pragma unroll
        for (int i = 0; i < INVN; ++i) acc += iv[i]*inv_w[i*RH + r];
        inv_all[tn*RH + r] = fmaxf(acc, 0.f);
        const int* pp = pa + tn*4;
        float s = 0.f;
        #pragma unroll
        for (int j = 0; j < 4; ++j) s += emb_lower[pp[j]*LE + r];
        pa_all[tn*LE + r] = s;
    } else {                           // zero rendezvous counters + flags (36992 ints)
        int idx = (b - 2016)*256 + tid;
        if (idx < 36992) flags[idx] = 0;
    }
}

// ---------------- merged prep 2: zmp, zip, ump/dmp, uip/dip, p0 init ----------------
__global__ __launch_bounds__(256) void k_prep2(
    const float* M, const float* inv_all, const float* pa_all,
    const float* zw, const float* zb,
    const float* uw, const float* ub, const float* dw, const float* db,
    const int* p0, int* p_arr, int* pflag,
    float* zmp, float* zip, float* ump, float* dmp, float* uip, float* dip) {
    int b = blockIdx.x, tid = threadIdx.x;
    if (b < 256) {                     // zmp = M @ zw[0:128]
        int cb = b & 1, rb = b >> 1;
        __shared__ float At[32][E_];
        for (int idx = tid; idx < 32*E_; idx += 256) {
            int r = idx >> 7, k = idx & 127;
            At[r][k] = M[(rb*32 + r)*E_ + k];
        }
        __syncthreads();
        float acc[32];
        #pragma unroll
        for (int r = 0; r < 32; ++r) acc[r] = 0.f;
        int col = cb*256 + tid;
        #pragma unroll 4
        for (int k = 0; k < E_; ++k) {
            float w = zw[k*HD + col];
            #pragma unroll
            for (int r = 0; r < 32; ++r) acc[r] += At[r][k]*w;
        }
        #pragma unroll
        for (int r = 0; r < 32; ++r)
            zmp[(size_t)(rb*32 + r)*HD + col] = acc[r];
    } else if (b < 384) {              // zip = [inv|pa] @ zw[192:320] + zb
        int b2 = b - 256;
        int cb = b2 & 1, rb = b2 >> 1;
        __shared__ float At2[32][E_];
        for (int idx = tid; idx < 32*E_; idx += 256) {
            int r = idx >> 7, k = idx & 127;
            int row = rb*32 + r;
            At2[r][k] = (k < 64) ? inv_all[row*RH + k] : pa_all[row*LE + (k - 64)];
        }
        __syncthreads();
        float acc[32];
        #pragma unroll
        for (int r = 0; r < 32; ++r) acc[r] = 0.f;
        int col = cb*256 + tid;
        #pragma unroll 4
        for (int k = 0; k < E_; ++k) {
            float w = zw[(192 + k)*HD + col];
            #pragma unroll
            for (int r = 0; r < 32; ++r) acc[r] += At2[r][k]*w;
        }
        float bb = zb[col];
        #pragma unroll
        for (int r = 0; r < 32; ++r)
            zip[(size_t)(rb*32 + r)*HD + col] = acc[r] + bb;
    } else if (b < 448) {              // ump/dmp from M
        int wg = b - 384;
        __shared__ float Mt[64][E_];
        for (int idx = tid; idx < 64*E_; idx += 256)
            ((float*)Mt)[idx] = M[(size_t)wg*64*E_ + idx];
        __syncthreads();
        int r = tid >> 2, q = tid & 3;
        float au = 0.f, ad = 0.f;
        #pragma unroll 4
        for (int k = 0; k < E_; ++k) {
            float m = Mt[r][k];
            au += m*uw[k*NE + q];
            if (q < 2) ad += m*dw[k*2 + q];
        }
        int row = wg*64 + r;
        ump[row*NE + q] = au;
        if (q < 2) dmp[row*2 + q] = ad;
    } else if (b < 480) {              // uip/dip from inv/pa
        int wg = b - 448;
        __shared__ float At3[64][E_];
        for (int idx = tid; idx < 64*E_; idx += 256) {
            int r = idx >> 7, k = idx & 127;
            int row = wg*64 + r;
            At3[r][k] = (k < 64) ? inv_all[row*RH + k] : pa_all[row*LE + (k - 64)];
        }
        __syncthreads();
        int r = tid >> 2, q = tid & 3;
        float au = ub[q], ad = (q < 2) ? db[q] : 0.f;
        #pragma unroll 4
        for (int k = 0; k < E_; ++k) {
            float v = At3[r][k];
            au += v*uw[(192 + k)*NE + q];
            if (q < 2) ad += v*dw[(192 + k)*2 + q];
        }
        int row = wg*64 + r;
        uip[row*NE + q] = au;
        if (q < 2) dip[row*2 + q] = ad;
    } else {                           // p0 -> p_arr[0], pflag[0]=ready
        if (tid < 64) {
            p_arr[tid] = p0[tid];
            pflag[tid] = 1;
        }
    }
}

// ---------------- kern_all: [n*64+p][9216] = M[row] @ kernel_w + b ----------------
// grid (72 colblocks x 32 rowblocks), 256 thr, 128x128 C-tile, K chunked by 32.
__global__ __launch_bounds__(256) void k_kern_all(const float* M, const float* kernel_w,
                                                  const float* kernel_b, float* kern_all) {
    int cb = blockIdx.x, rb = blockIdx.y;
    int tid = threadIdx.x;
    int ty = tid >> 4, tx = tid & 15;
    __shared__ float As[128][36];
    __shared__ float Bs[32][128];
    float acc[8][8];
    #pragma unroll
    for (int i = 0; i < 8; ++i)
        #pragma unroll
        for (int j = 0; j < 8; ++j) acc[i][j] = 0.f;

    for (int kc = 0; kc < 4; ++kc) {
        // stage A chunk: 128 rows x 32 k
        #pragma unroll
        for (int l = 0; l < 4; ++l) {
            int idx = tid + l*256;            // 1024 float4s
            int r = idx >> 3, kq = idx & 7;
            float4 v = *(const float4*)&M[(size_t)(rb*128 + r)*E_ + kc*32 + kq*4];
            As[r][kq*4+0] = v.x; As[r][kq*4+1] = v.y; As[r][kq*4+2] = v.z; As[r][kq*4+3] = v.w;
        }
        // stage B chunk: 32 k x 128 cols
        #pragma unroll
        for (int l = 0; l < 4; ++l) {
            int idx = tid + l*256;
            int k = idx >> 5, cq = idx & 31;
            *(float4*)&Bs[k][cq*4] = *(const float4*)&kernel_w[(size_t)(kc*32 + k)*KCOLS + cb*128 + cq*4];
        }
        __syncthreads();
        for (int kk = 0; kk < 32; ++kk) {
            float a[8];
            #pragma unroll
            for (int i = 0; i < 8; ++i) a[i] = As[ty*8 + i][kk];
            float4 b0 = *(const float4*)&Bs[kk][tx*8];
            float4 b1 = *(const float4*)&Bs[kk][tx*8 + 4];
            #pragma unroll
            for (int i = 0; i < 8; ++i) {
                acc[i][0] = fmaf(a[i], b0.x, acc[i][0]);
                acc[i][1] = fmaf(a[i], b0.y, acc[i][1]);
                acc[i][2] = fmaf(a[i], b0.z, acc[i][2]);
                acc[i][3] = fmaf(a[i], b0.w, acc[i][3]);
                acc[i][4] = fmaf(a[i], b1.x, acc[i][4]);
                acc[i][5] = fmaf(a[i], b1.y, acc[i][5]);
                acc[i][6] = fmaf(a[i], b1.z, acc[i][6]);
                acc[i][7] = fmaf(a[i], b1.w, acc[i][7]);
            }
        }
        __syncthreads();
    }
    float kb[8];
    #pragma unroll
    for (int j = 0; j < 8; ++j) kb[j] = kernel_b[cb*128 + tx*8 + j];
    #pragma unroll
    for (int i = 0; i < 8; ++i) {
        size_t row = (size_t)rb*128 + ty*8 + i;
        float4 o0, o1;
        o0.x = acc[i][0]+kb[0]; o0.y = acc[i][1]+kb[1]; o0.z = acc[i][2]+kb[2]; o0.w = acc[i][3]+kb[3];
        o1.x = acc[i][4]+kb[4]; o1.y = acc[i][5]+kb[5]; o1.z = acc[i][6]+kb[6]; o1.w = acc[i][7]+kb[7];
        *(float4*)&kern_all[row*KCOLS + cb*128 + tx*8]     = o0;
        *(float4*)&kern_all[row*KCOLS + cb*128 + tx*8 + 4] = o1;
    }
}

// giM[dir][n][l][g] = M[n][l] . wi[g] + bi[g]
__global__ __launch_bounds__(384) void k_giM(const float* M, const float* wiT4,
                                             const float* bif, const float* bib, float* giM) {
    int lblk = blockIdx.x, n = blockIdx.y, dir = blockIdx.z;
    int g = threadIdx.x;
    __shared__ float Ml[8][E_];
    for (int idx = g; idx < 8*E_; idx += 384) {
        int r = idx >> 7, k = idx & 127;
        Ml[r][k] = M[(n*NL + lblk*8 + r)*E_ + k];
    }
    __syncthreads();
    float acc[8];
    #pragma unroll
    for (int r = 0; r < 8; ++r) acc[r] = 0.f;
    const float4* W = (const float4*)(wiT4) + dir*32*384;
    for (int kq = 0; kq < 32; ++kq) {
        float4 w = W[kq*384 + g];
        #pragma unroll
        for (int r = 0; r < 8; ++r) {
            float4 h = *(const float4*)&Ml[r][kq*4];
            acc[r] += w.x*h.x + w.y*h.y + w.z*h.z + w.w*h.w;
        }
    }
    float bi = dir ? bib[g] : bif[g];
    #pragma unroll
    for (int r = 0; r < 8; ++r)
        giM[((dir*N_ + n)*NL + lblk*8 + r)*G3 + g] = acc[r] + bi;
}

// ---------------- MFMA GRU: 512 wgs, XCD-swizzled so the 4 pblk-wgs of a (dir,n)
// slice land on one XCD (blockIdx%8 = XCD round-robin) -> giM stays in that L2.
__global__ __launch_bounds__(256, 2) void k_gru(const float* giM, const _Float16* WBpack,
                                                const float* bhf, const float* bhb,
                                                const float* beta_w, const float* beta_b,
                                                float* Ball) {
    int b = blockIdx.x;
    int x = b & 7, m = b >> 3;
    int pblk = m & 3;
    int s = x + 8*(m >> 2);
    int dir = s >> 6, n = s & 63;
    int tid = threadIdx.x;
    int w = tid >> 6;
    int lane = tid & 63;
    int quad = lane >> 4;
    int col  = lane & 15;

    __shared__ _Float16 Hhi[16*136];
    __shared__ _Float16 Hlo[16*136];
    __shared__ float    Hf[16*132];
    __shared__ float    bwT[4*132];
    for (int idx = tid; idx < 16*136; idx += 256) { Hhi[idx] = (_Float16)0.f; Hlo[idx] = (_Float16)0.f; }
    for (int idx = tid; idx < 16*132; idx += 256) Hf[idx] = 0.f;
    for (int idx = tid; idx < 512; idx += 256) { int k = idx >> 2, e = idx & 3; bwT[e*132 + k] = beta_w[k*NE + e]; }

    half8 WB[48];
    const half8* wsrc = (const half8*)(WBpack) + ((size_t)(dir*4 + w)*4)*12*64;
    #pragma unroll
    for (int f = 0; f < 48; ++f) WB[f] = wsrc[(size_t)f*64 + lane];

    const float* bh = dir ? bhb : bhf;
    float bhv[6];
    #pragma unroll
    for (int gt2 = 0; gt2 < 3; ++gt2) {
        bhv[gt2*2+0] = bh[gt2*128 + w*32 + col];
        bhv[gt2*2+1] = bh[gt2*128 + w*32 + col + 16];
    }
    const float* giBase = giM + (size_t)(dir*N_ + n)*NL*G3;

    int bseq = tid >> 4, bsub = tid & 15, bee = bsub & 3, bpart = bsub >> 2;
    float bbias = beta_b[bee];
    __syncthreads();

    for (int j = 0; j < NL; ++j) {
        floatx4 C[6];
        #pragma unroll
        for (int reg = 0; reg < 4; ++reg) {
            int seq = quad*4 + reg;
            int p = pblk*16 + seq;
            int l = dir ? ((p + 63 - j) & 63) : ((p + j) & 63);
            const float* gl = giBase + l*G3 + w*32 + col;
            #pragma unroll
            for (int gt2 = 0; gt2 < 2; ++gt2)
                #pragma unroll
                for (int isub = 0; isub < 2; ++isub)
                    C[gt2*2 + isub][reg] = gl[gt2*128 + isub*16] + bhv[gt2*2+isub];
            #pragma unroll
            for (int isub = 0; isub < 2; ++isub)
                C[4 + isub][reg] = bhv[4+isub];
        }
        #pragma unroll
        for (int kt = 0; kt < 4; ++kt) {
            int off = col*136 + kt*32 + quad*8;
            half8 ahi = *(const half8*)&Hhi[off];
            half8 alo = *(const half8*)&Hlo[off];
            #pragma unroll
            for (int nt = 0; nt < 6; ++nt) {
                half8 bhi2 = WB[kt*12 + nt];
                half8 blo2 = WB[kt*12 + 6 + nt];
                C[nt] = __builtin_amdgcn_mfma_f32_16x16x32_f16(ahi, bhi2, C[nt], 0,0,0);
                C[nt] = __builtin_amdgcn_mfma_f32_16x16x32_f16(alo, bhi2, C[nt], 0,0,0);
                C[nt] = __builtin_amdgcn_mfma_f32_16x16x32_f16(ahi, blo2, C[nt], 0,0,0);
            }
        }
        __syncthreads();

        #pragma unroll
        for (int reg = 0; reg < 4; ++reg) {
            int seq = quad*4 + reg;
            int p = pblk*16 + seq;
            int l = dir ? ((p + 63 - j) & 63) : ((p + j) & 63);
            const float* gl = giBase + l*G3 + 256 + w*32 + col;
            #pragma unroll
            for (int isub = 0; isub < 2; ++isub) {
                int i = w*32 + isub*16 + col;
                float r  = fsig(C[isub][reg]);
                float z  = fsig(C[2 + isub][reg]);
                float nn = ftanh(gl[isub*16] + r*C[4 + isub][reg]);
                float hold = Hf[seq*132 + i];
                float hnew = (1.f - z)*nn + z*hold;
                _Float16 hi = (_Float16)hnew;
                _Float16 lo = (_Float16)(hnew - (float)hi);
                Hf[seq*132 + i] = hnew;
                Hhi[seq*136 + i] = hi;
                Hlo[seq*136 + i] = lo;
            }
        }
        __syncthreads();

        {
            float acc = 0.f;
            const float* hrow = &Hf[bseq*132];
            const float* brow = &bwT[bee*132];
            #pragma unroll 8
            for (int kk = 0; kk < 32; ++kk) {
                int k2 = bpart + 4*kk;
                acc += hrow[k2]*brow[k2];
            }
            acc += __shfl_xor(acc, 4);
            acc += __shfl_xor(acc, 8);
            if (bpart == 0) {
                float bval = fsig(acc + bbias);
                int p = pblk*16 + bseq;
                Ball[((n*NL + p)*128 + 2*j + dir)*NE + bee] = bval;
            }
        }
    }
}

// stick-breaking -> reordered P_final[n][p][j][e]
__global__ __launch_bounds__(64) void k_P(const float* Ball, float* Pall) {
    int np = blockIdx.x;
    int tid = threadIdx.x;
    __shared__ float B[128][NE];
    __shared__ float Pf[128][NE];
    const float* src = Ball + np*128*NE;
    for (int idx = tid; idx < 128*NE; idx += 64) ((float*)B)[idx] = src[idx];
    __syncthreads();
    if (tid < NE) {
        int e = tid;
        float c = 1.f;
        for (int j2 = 0; j2 < 128; ++j2) {
            float bz = (j2 == 0 || j2 == 127) ? 0.f : B[j2][e];
            float bf = (j2 == 127) ? 1.f : bz;
            Pf[j2][e] = bf * c;
            c *= (1.f - bz);
        }
    }
    __syncthreads();
    float* dst = Pall + np*128*NE;
    for (int idx = tid; idx < 128*NE; idx += 64) {
        int j = idx >> 2, e = idx & 3;
        int jf = (j < 64) ? (2*(63 - j) + 1) : (2*(j - 64));
        dst[idx] = Pf[jf][e];
    }
}

// ---------------- persistent T-loop: ONE dispatch, 256 wgs (1/CU), loops t ----------
// wg (q = b&3, n = b>>2). Per t: wait pflag[t][n] -> kern slice from kern_all ->
// conv quarter -> 4-wide h1 rendezvous -> q0 heads -> publish p for t+1.
__global__ __launch_bounds__(256, 1) void k_step(
    const float* obs, const float* kern_all, const float* conv_bias,
    float* h1_buf,
    const float* zmp, const float* zip,
    const float* ump, const float* uip, const float* dmp, const float* dip,
    const float* zw, const float* aw, const float* ab,
    const float* uw, const float* dw, const float* cw, const float* cb,
    const float* amask, const float* Pall,
    float* out, int* p_arr, int* pflag, int* cnt) {

    int wg = blockIdx.x, tid = threadIdx.x;
    int q = wg & 3, n = wg >> 2;

    __shared__ __align__(16) float obs_l[D_*HW*20];   // 20480 B
    __shared__ float kl[2304];
    __shared__ float h1s[CH];
    __shared__ float hs[832];                         // heads scratch
    __shared__ int   ps[4];

    for (int t = 0; t < T_; ++t) {
        __syncthreads();   // guard LDS reuse across iterations

        // stage obs tile (independent of p)
        const float4* op4 = (const float4*)(obs + (size_t)(t*N_ + n)*D_*HW*HW);
        #pragma unroll
        for (int k = 0; k < 4; ++k) {
            int idx = tid + k*256;
            int d = idx >> 6, rem = idx & 63;
            int y = rem >> 2, xq = rem & 3;
            *(float4*)&obs_l[d*320 + y*20 + xq*4] = op4[idx];
        }
        // wait pointer flag for step t
        if (tid == 0) {
            while (__hip_atomic_load(&pflag[t*64 + n], __ATOMIC_RELAXED, __HIP_MEMORY_SCOPE_AGENT) == 0)
                __builtin_amdgcn_s_sleep(1);
            (void)__hip_atomic_load(&pflag[t*64 + n], __ATOMIC_ACQUIRE, __HIP_MEMORY_SCOPE_AGENT);
            ps[0] = p_arr[t*64 + n];
        }
        __syncthreads();
        int p = ps[0];

        // kern slice
        const float4* ksrc = (const float4*)(kern_all + ((size_t)(n*NL + p)*KCOLS + q*2304));
        #pragma unroll
        for (int l = 0; l < 3; ++l) {
            int i = tid + l*256;
            if (i < 576) ((float4*)kl)[i] = ksrc[i];
        }
        __syncthreads();

        // conv quarter
        {
            int c = tid >> 4, y = tid & 15;
            float acc[16];
            #pragma unroll
            for (int x = 0; x < 16; ++x) acc[x] = 0.f;
            for (int d = 0; d < D_; ++d) {
                const float* kd = &kl[c*144 + d*9];
                #pragma unroll
                for (int ky = 0; ky < 3; ++ky) {
                    int yy = y + ky - 1;
                    if (yy < 0 || yy >= HW) continue;
                    const float4* rs = (const float4*)&obs_l[(d*16 + yy)*20];
                    float4 r0 = rs[0], r1 = rs[1], r2 = rs[2], r3 = rs[3];
                    float row[18];
                    row[0] = 0.f; row[17] = 0.f;
                    row[1]=r0.x; row[2]=r0.y; row[3]=r0.z; row[4]=r0.w;
                    row[5]=r1.x; row[6]=r1.y; row[7]=r1.z; row[8]=r1.w;
                    row[9]=r2.x; row[10]=r2.y; row[11]=r2.z; row[12]=r2.w;
                    row[13]=r3.x; row[14]=r3.y; row[15]=r3.z; row[16]=r3.w;
                    float k0 = kd[ky*3], k1 = kd[ky*3+1], k2 = kd[ky*3+2];
                    #pragma unroll
                    for (int x = 0; x < 16; ++x)
                        acc[x] += row[x]*k0 + row[x+1]*k1 + row[x+2]*k2;
                }
            }
            float bc = conv_bias[q*16 + c];
            float psum = 0.f;
            #pragma unroll
            for (int x = 0; x < 16; ++x) psum += fmaxf(acc[x] + bc, 0.f);
            psum += __shfl_xor(psum, 1);
            psum += __shfl_xor(psum, 2);
            psum += __shfl_xor(psum, 4);
            psum += __shfl_xor(psum, 8);
            if (y == 0) {
                if (q == 0) h1s[c] = psum;
                else        h1_buf[(size_t)(t*64 + n)*64 + q*16 + c] = psum;
            }
        }
        __syncthreads();   // drains stores (vmcnt0) before release

        if (q != 0) {
            if (tid == 0)
                __hip_atomic_fetch_add(&cnt[(t*64 + n)*16], 1, __ATOMIC_RELEASE, __HIP_MEMORY_SCOPE_AGENT);
            continue;      // next t (waits on pflag[t+1])
        }

        // 4-wide rendezvous on h1
        if (tid == 0) {
            while (__hip_atomic_load(&cnt[(t*64 + n)*16], __ATOMIC_RELAXED, __HIP_MEMORY_SCOPE_AGENT) < 3)
                __builtin_amdgcn_s_sleep(1);
            (void)__hip_atomic_load(&cnt[(t*64 + n)*16], __ATOMIC_ACQUIRE, __HIP_MEMORY_SCOPE_AGENT);
        }
        __syncthreads();
        if (tid < 48) h1s[16 + tid] = h1_buf[(size_t)(t*64 + n)*64 + 16 + tid];
        __syncthreads();

        // heads
        {
            float* z1s   = hs;                    // 512
            float* pla   = z1s + 512;             // 128
            float* pc    = pla + 128;             // 32
            float* la    = pc + 32;               // 16
            float* lu    = la + 16;               // 4
            float* ld2   = lu + 4;                // 2
            float* uvals = ld2 + 2;               // 4
            float* dp    = uvals + 4;             // 128
            float* sc    = dp + 128;              // 1

            size_t ob = ((size_t)t*N_ + n)*OUTW;
            const float* zmpp = zmp + (size_t)(n*NL + p)*HD;
            const float* zipp = zip + (size_t)(t*N_ + n)*HD;
            #pragma unroll
            for (int hh = 0; hh < 2; ++hh) {
                int h = tid + hh*256;
                float acc = zmpp[h] + zipp[h];
                #pragma unroll 8
                for (int c = 0; c < CH; ++c) acc += h1s[c]*zw[(E_ + c)*HD + h];
                float v = fmaxf(acc, 0.f);
                z1s[h] = v;
                out[ob + 146 + h] = v;
            }
            __syncthreads();

            if (tid < 128) {
                int a2 = tid >> 3, part = tid & 7;
                float acc = 0.f;
                const float* z0 = z1s + part*64;
                #pragma unroll 8
                for (int h = 0; h < 64; ++h) acc += z0[h]*aw[(part*64 + h)*A_ + a2];
                pla[a2*8 + part] = acc;
            } else if (tid < 160) {
                int part = tid - 128;
                float acc = 0.f;
                const float* z0 = z1s + part*16;
                #pragma unroll 8
                for (int h = 0; h < 16; ++h) acc += z0[h]*cw[part*16 + h];
                pc[part] = acc;
            } else if (tid < 164) {
                int e = tid - 160;
                float acc = ump[(n*NL + p)*NE + e] + uip[(t*N_ + n)*NE + e];
                #pragma unroll 8
                for (int c = 0; c < CH; ++c) acc += h1s[c]*uw[(E_ + c)*NE + e];
                lu[e] = acc;
            } else if (tid < 166) {
                int g = tid - 164;
                float acc = dmp[(n*NL + p)*2 + g] + dip[(t*N_ + n)*2 + g];
                #pragma unroll 8
                for (int c = 0; c < CH; ++c) acc += h1s[c]*dw[(E_ + c)*2 + g];
                ld2[g] = acc;
            }
            __syncthreads();
            if (tid < A_) {
                float acc = ab[tid];
                #pragma unroll
                for (int k = 0; k < 8; ++k) acc += pla[tid*8 + k];
                la[tid] = acc;
            } else if (tid == 24) {
                float acc = cb[0];
                #pragma unroll
                for (int k = 0; k < 32; ++k) acc += pc[k];
                sc[0] = acc;
            }
            __syncthreads();

            if (tid == 0) {
                float mx = la[0];
                #pragma unroll
                for (int k2 = 1; k2 < A_; ++k2) mx = fmaxf(mx, la[k2]);
                float pr[A_]; float sum = 0.f;
                #pragma unroll
                for (int k2 = 0; k2 < A_; ++k2) { pr[k2] = expf(la[k2]-mx); sum += pr[k2]; }
                const float* am = amask + ((size_t)t*N_ + n)*A_;
                float best = -1.f; int bi2 = 0;
                #pragma unroll
                for (int k2 = 0; k2 < A_; ++k2) {
                    float v = pr[k2]/sum * am[k2];
                    out[ob + 1 + k2] = v;
                    if (v > best) { best = v; bi2 = k2; }
                }
                out[ob + 0] = (float)bi2;
            } else if (tid == 1) {
                float mx = fmaxf(fmaxf(lu[0], lu[1]), fmaxf(lu[2], lu[3]));
                float ev[NE]; float s0 = 0.f;
                #pragma unroll
                for (int e = 0; e < NE; ++e) { ev[e] = expf(lu[e]-mx); s0 += ev[e]; }
                #pragma unroll
                for (int e = 0; e < NE; ++e) uvals[e] = ev[e]/s0;
            } else if (tid == 2) {
                float mx = fmaxf(ld2[0], ld2[1]);
                float e0 = expf(ld2[0]-mx), e1 = expf(ld2[1]-mx);
                float s0 = e0 + e1;
                out[ob + 660] = e0/s0;
                out[ob + 661] = e1/s0;
                int dg = (ld2[1] > ld2[0]) ? 1 : 0;
                ps[2] = dg;
                out[ob + 662] = (float)dg;
            }
            __syncthreads();
            if (tid < 128) {
                const float* Pp = Pall + ((size_t)(n*NL + p)*128 + tid)*NE;
                float v = Pp[0]*uvals[0] + Pp[1]*uvals[1] + Pp[2]*uvals[2] + Pp[3]*uvals[3];
                dp[tid] = v;
                out[ob + 18 + tid] = v;
            }
            __syncthreads();
            if (tid == 0) {
                int dsel;
                if (ps[2] == 1) {
                    float best = dp[0]; dsel = 0;
                    for (int j2 = 1; j2 < 128; ++j2) if (dp[j2] > best) { best = dp[j2]; dsel = j2; }
                } else dsel = 64;
                int pn = p + dsel - 64;
                pn = pn < 0 ? 0 : (pn > 63 ? 63 : pn);
                out[ob + 17]  = (float)dsel;
                out[ob + 658] = (float)pn;
                out[ob + 659] = sc[0];
                // publish pointer for step t+1
                p_arr[(t+1)*64 + n] = pn;
                __hip_atomic_store(&pflag[(t+1)*64 + n], 1, __ATOMIC_RELEASE, __HIP_MEMORY_SCOPE_AGENT);
            }
        }
    }
}

extern "C" void kernel_launch(void* const* d_in, const int* in_sizes, int n_in,
                              void* d_out, int out_size, void* d_ws, size_t ws_size,
                              hipStream_t stream) {
    (void)in_sizes; (void)n_in; (void)out_size; (void)ws_size;
    const int*   lines    = (const int*)  d_in[0];
    const float* obs      = (const float*)d_in[1];
    const float* invent   = (const float*)d_in[2];
    const int*   pa       = (const int*)  d_in[3];
    const float* amask    = (const float*)d_in[4];
    const int*   p0       = (const int*)  d_in[5];
    const float* emb_task = (const float*)d_in[6];
    const float* emb_low  = (const float*)d_in[7];
    const float* wi_f     = (const float*)d_in[8];
    const float* wh_f     = (const float*)d_in[9];
    const float* bi_f     = (const float*)d_in[10];
    const float* bh_f     = (const float*)d_in[11];
    const float* wi_b     = (const float*)d_in[12];
    const float* wh_b     = (const float*)d_in[13];
    const float* bi_b     = (const float*)d_in[14];
    const float* bh_b     = (const float*)d_in[15];
    const float* beta_w   = (const float*)d_in[16];
    const float* beta_b   = (const float*)d_in[17];
    const float* kernel_w = (const float*)d_in[18];
    const float* kernel_b = (const float*)d_in[19];
    const float* conv_b   = (const float*)d_in[20];
    const float* inv_w    = (const float*)d_in[21];
    const float* inv_b    = (const float*)d_in[22];
    const float* zw       = (const float*)d_in[23];
    const float* zb       = (const float*)d_in[24];
    const float* aw       = (const float*)d_in[25];
    const float* ab       = (const float*)d_in[26];
    const float* uw       = (const float*)d_in[27];
    const float* ub       = (const float*)d_in[28];
    const float* dw       = (const float*)d_in[29];
    const float* db       = (const float*)d_in[30];
    const float* cw       = (const float*)d_in[31];
    const float* cb       = (const float*)d_in[32];
    float* out = (float*)d_out;

    float* ws = (float*)d_ws;
    size_t off = 0;
    float* M        = ws + off; off += (size_t)N_*NL*E_;
    float* wiT4     = ws + off; off += 2*32*384*4;
    _Float16* WBpack = (_Float16*)(ws + off); off += (size_t)384*512/2;
    float* giM      = ws + off; off += (size_t)2*N_*NL*G3;
    float* Ball     = ws + off; off += (size_t)N_*NL*128*NE;
    float* Pall     = ws + off; off += (size_t)N_*NL*128*NE;
    float* inv_all  = ws + off; off += (size_t)T_*N_*RH;
    float* pa_all   = ws + off; off += (size_t)T_*N_*LE;
    float* kern_all = ws + off; off += (size_t)N_*NL*KCOLS;   // 151 MB
    float* h1_buf   = ws + off; off += (size_t)T_*N_*64;
    float* zmp      = ws + off; off += (size_t)N_*NL*HD;
    float* zip      = ws + off; off += (size_t)T_*N_*HD;
    float* ump      = ws + off; off += (size_t)N_*NL*NE;
    float* dmp      = ws + off; off += (size_t)N_*NL*2;
    float* uip      = ws + off; off += (size_t)T_*N_*NE;
    float* dip      = ws + off; off += (size_t)T_*N_*2;
    int*   flags    = (int*)(ws + off); off += 36992;
    int*   cnt      = flags;              // 32*64*16
    int*   pflag    = flags + 32768;      // 33*64
    int*   p_arr    = pflag + 2112;       // 33*64

    k_prep1<<<2161, 256, 0, stream>>>(lines, emb_task, M, wi_f, wi_b, wiT4,
                                      wh_f, wh_b, WBpack,
                                      invent, inv_w, inv_b, pa, emb_low, inv_all, pa_all, flags);
    k_prep2<<<481, 256, 0, stream>>>(M, inv_all, pa_all, zw, zb, uw, ub, dw, db,
                                     p0, p_arr, pflag, zmp, zip, ump, dmp, uip, dip);
    k_kern_all<<<dim3(72, 32), 256, 0, stream>>>(M, kernel_w, kernel_b, kern_all);
    k_giM<<<dim3(8, N_, 2), 384, 0, stream>>>(M, wiT4, bi_f, bi_b, giM);
    k_gru<<<512, 256, 0, stream>>>(giM, WBpack, bh_f, bh_b, beta_w, beta_b, Ball);
    k_P<<<N_*NL, 64, 0, stream>>>(Ball, Pall);

    k_step<<<256, 256, 0, stream>>>(obs, kern_all, conv_b, h1_buf,
                                    zmp, zip, ump, uip, dmp, dip,
                                    zw, aw, ab, uw, dw, cw, cb,
                                    amask, Pall, out, p_arr, pflag, cnt);
}